// Round 3
// baseline (2893.065 us; speedup 1.0000x reference)
//
#include <hip/hip_runtime.h>
#include <cfloat>
#include <cmath>

#define B_ 4
#define N_ 16384
#define M_ 512
#define C_ 128
#define K_ 16
#define L_ 6
#define STEPS_ 5

// ---------------- wave helpers (wave64) ----------------
__device__ inline unsigned long long wave_min_u64(unsigned long long v) {
#pragma unroll
  for (int m = 1; m < 64; m <<= 1) {
    unsigned long long o = __shfl_xor(v, m, 64);
    v = (o < v) ? o : v;
  }
  return v;
}
__device__ inline float wave_sum(float v) {
#pragma unroll
  for (int m = 1; m < 64; m <<= 1) v += __shfl_xor(v, m, 64);
  return v;
}

// ---------------- encoder ----------------
__global__ __launch_bounds__(256) void k_encode(
    const float* __restrict__ xyz, const float* __restrict__ w1,
    const float* __restrict__ b1, const float* __restrict__ w2,
    const float* __restrict__ b2, float* __restrict__ feats) {
  __shared__ __align__(16) float s_w2[128 * 68];
  __shared__ __align__(16) float s_xyz[32 * 3];
  __shared__ __align__(16) float s_h[32 * 68];
  int t = threadIdx.x;
  for (int i = t; i < 128 * 64; i += 256) {
    int c = i >> 6, j = i & 63;
    s_w2[c * 68 + j] = w2[i];
  }
  int p0 = blockIdx.x * 32;
  for (int i = t; i < 96; i += 256) s_xyz[i] = xyz[(size_t)p0 * 3 + i];
  __syncthreads();
  int p = t >> 3, q = t & 7;
  float x0 = s_xyz[p * 3], x1 = s_xyz[p * 3 + 1], x2 = s_xyz[p * 3 + 2];
#pragma unroll
  for (int cc = 0; cc < 8; ++cc) {
    int c = q * 8 + cc;
    float a = b1[c] + w1[c * 3] * x0 + w1[c * 3 + 1] * x1 + w1[c * 3 + 2] * x2;
    s_h[p * 68 + c] = fmaxf(a, 0.f);
  }
  __syncthreads();
#pragma unroll
  for (int cc = 0; cc < 16; ++cc) {
    int c = q + cc * 8;
    float acc = b2[c];
    const float* wr = &s_w2[c * 68];
    const float* hr = &s_h[p * 68];
#pragma unroll
    for (int j = 0; j < 64; j += 4) {
      float4 w4 = *(const float4*)&wr[j];
      float4 h4 = *(const float4*)&hr[j];
      acc += w4.x * h4.x + w4.y * h4.y + w4.z * h4.z + w4.w * h4.w;
    }
    feats[(size_t)(p0 + p) * 128 + c] = acc;
  }
}

// ---------------- per-step init ----------------
__global__ __launch_bounds__(128) void k_step_init(
    const float* __restrict__ feats, const int* __restrict__ start,
    int* __restrict__ idxbuf, float* __restrict__ walks) {
  int g = blockIdx.x;
  int c = threadIdx.x;
  int b = g >> 9;
  int s = start[g];
  walks[(size_t)g * 768 + c] = feats[((size_t)b * N_ + s) * 128 + c];
  if (c == 0) idxbuf[g] = s;
}

// ---------------- selector: exact 17-NN + gumbel argmax ----------------
// 256 threads (4 waves) per walker; d2 register-cached (single distance pass).
#define D2_CACHE(PX, PY, PZ, SLOT)                        \
  {                                                       \
    float dx = (PX)-qx, dy = (PY)-qy, dz = (PZ)-qz;       \
    float xx = dx * dx, yy = dy * dy, zz = dz * dz;       \
    float d2 = (xx + yy) + zz;                            \
    d2c[SLOT] = d2;                                       \
    if (d2 < best) { best = d2; bs = (SLOT); }            \
  }

__global__ __launch_bounds__(256) void k_select(
    const float* __restrict__ pos, const float* __restrict__ feats,
    int* __restrict__ idxbuf, float* __restrict__ walks,
    const float* __restrict__ beta_w, const float* __restrict__ beta_b,
    const float* __restrict__ gamma_w, const float* __restrict__ gamma_b,
    const float* __restrict__ gumb, int l) {
  __shared__ __align__(16) float s_f[128];
  __shared__ __align__(16) float s_q[128];
  __shared__ __align__(16) float s_g[128];
  __shared__ float s_qb;
  __shared__ float s_tau;
  __shared__ float s_logit[16];
  __shared__ unsigned long long s_keys[256];
  __shared__ unsigned long long s_cand[192];
  __shared__ unsigned int s_knn[17];
  __shared__ int s_cnt;
  __shared__ int s_bestn;

  int g = blockIdx.x, t = threadIdx.x;
  int lane = t & 63, w = t >> 6;
  int b = g >> 9, mm = g & (M_ - 1);
  int idx0 = idxbuf[g];
  if (t < 128) s_f[t] = feats[((size_t)b * N_ + idx0) * 128 + t];
  if (t == 0) s_cnt = 0;
  __syncthreads();

  if (t < 128) {
    float aq = beta_b[t];
#pragma unroll 4
    for (int j = 0; j < 128; j += 4) {
      float4 w4 = *(const float4*)&beta_w[(size_t)t * 128 + j];
      float4 f4 = *(const float4*)&s_f[j];
      aq += w4.x * f4.x + w4.y * f4.y + w4.z * f4.z + w4.w * f4.w;
    }
    s_q[t] = aq;
  }
  __syncthreads();
  if (t < 128) {
    float gg = 0.f;
    for (int cidx = 0; cidx < 128; ++cidx)
      gg += s_q[cidx] * gamma_w[(size_t)cidx * 128 + t];
    s_g[t] = gg;
  }
  if (w == 0) {
    float qbp = s_q[lane] * gamma_b[lane] + s_q[lane + 64] * gamma_b[lane + 64];
    float qb = wave_sum(qbp);
    if (lane == 0) s_qb = qb;
  }

  const float* pp = pos + ((size_t)b * N_ + idx0) * 3;
  float qx = pp[0], qy = pp[1], qz = pp[2];
  const float* pb = pos + (size_t)b * N_ * 3;

  // single distance pass: per-thread min + full d2 register cache
  float best = FLT_MAX;
  int bs = 0;
  float d2c[64];
  {
#pragma clang fp contract(off)
#pragma unroll
    for (int it = 0; it < 16; ++it) {
      int j0 = w * 4096 + (it * 64 + lane) * 4;
      float4 p0 = *(const float4*)&pb[3 * j0];
      float4 p1 = *(const float4*)&pb[3 * j0 + 4];
      float4 p2 = *(const float4*)&pb[3 * j0 + 8];
      D2_CACHE(p0.x, p0.y, p0.z, it * 4 + 0)
      D2_CACHE(p0.w, p1.x, p1.y, it * 4 + 1)
      D2_CACHE(p1.z, p1.w, p2.x, it * 4 + 2)
      D2_CACHE(p2.y, p2.z, p2.w, it * 4 + 3)
    }
  }
  // slot -> global idx: j = w*4096 + (slot/4)*256 + lane*4 + slot%4
  int bi = w * 4096 + (bs >> 2) * 256 + lane * 4 + (bs & 3);
  s_keys[t] = ((unsigned long long)__float_as_uint(best) << 32) | (unsigned)bi;
  __syncthreads();
  // tau = 17th smallest of 256 thread minima (upper bound on exact 17th-NN)
  if (w == 0) {
    unsigned long long c0 = s_keys[lane], c1 = s_keys[lane + 64];
    unsigned long long c2 = s_keys[lane + 128], c3 = s_keys[lane + 192];
    unsigned long long kth = 0;
    for (int it = 0; it < 17; ++it) {
      unsigned long long l01 = c0 < c1 ? c0 : c1;
      unsigned long long l23 = c2 < c3 ? c2 : c3;
      unsigned long long lo = l01 < l23 ? l01 : l23;
      unsigned long long mn = wave_min_u64(lo);
      kth = mn;
      if (c0 == mn) c0 = ~0ULL;
      else if (c1 == mn) c1 = ~0ULL;
      else if (c2 == mn) c2 = ~0ULL;
      else if (c3 == mn) c3 = ~0ULL;
    }
    if (lane == 0) s_tau = __uint_as_float((unsigned)(kth >> 32));
  }
  __syncthreads();
  float tau = s_tau;

  // pass 2 from register cache: no loads, no recompute (bit-identical d2)
#pragma unroll
  for (int it = 0; it < 16; ++it) {
#pragma unroll
    for (int s = 0; s < 4; ++s) {
      float d2 = d2c[it * 4 + s];
      if (d2 <= tau) {
        int j = w * 4096 + it * 256 + lane * 4 + s;
        int p = atomicAdd(&s_cnt, 1);
        if (p < 192)
          s_cand[p] =
              ((unsigned long long)__float_as_uint(d2) << 32) | (unsigned)j;
      }
    }
  }
  __syncthreads();
  // exact top-17 by (d2, idx) key — matches jax.lax.top_k tie-breaking
  if (w == 0) {
    int cnt = s_cnt;
    if (cnt > 192) cnt = 192;
    unsigned long long c0 = (lane < cnt) ? s_cand[lane] : ~0ULL;
    unsigned long long c1 = (lane + 64 < cnt) ? s_cand[lane + 64] : ~0ULL;
    unsigned long long c2 = (lane + 128 < cnt) ? s_cand[lane + 128] : ~0ULL;
    for (int it = 0; it < 17; ++it) {
      unsigned long long l01 = c0 < c1 ? c0 : c1;
      unsigned long long lo = l01 < c2 ? l01 : c2;
      unsigned long long mn = wave_min_u64(lo);
      if (lane == 0) s_knn[it] = (unsigned)mn;
      if (c0 == mn) c0 = ~0ULL;
      else if (c1 == mn) c1 = ~0ULL;
      else if (c2 == mn) c2 = ~0ULL;
    }
  }
  __syncthreads();

  // logits: wave w handles neighbors w*4 .. w*4+3 (same butterfly as before)
#pragma unroll
  for (int kk = 0; kk < 4; ++kk) {
    int k = w * 4 + kk;
    unsigned nb = s_knn[k + 1];
    const float* fp = feats + ((size_t)b * N_ + nb) * 128;
    float pr = s_g[lane] * fp[lane] + s_g[lane + 64] * fp[lane + 64];
    float ssum = wave_sum(pr);
    if (lane == 0) s_logit[k] = ssum;
  }
  __syncthreads();
  if (t == 0) {
    const float* gbp = gumb + (((size_t)b) * M_ + mm) * K_;
    float qb = s_qb;
    float bestv = -FLT_MAX;
    int bestn = (int)s_knn[1];
    for (int k = 0; k < 16; ++k) {
      float logit = (s_logit[k] + qb) / sqrtf(128.0f);
      float tot = (logit + gbp[k]) / 0.1f;
      if (tot > bestv) { bestv = tot; bestn = (int)s_knn[k + 1]; }
    }
    s_bestn = bestn;
    idxbuf[g] = bestn;
  }
  __syncthreads();
  if (t < 128) {
    int bn = s_bestn;
    walks[(size_t)g * 768 + (size_t)(l + 1) * 128 + t] =
        feats[((size_t)b * N_ + bn) * 128 + t];
  }
}

// ---------------- route + predict + scatter ----------------
// 4 walkers per block (weight-load amortization), 256 threads.
// thread t: channel c = t&127, half = t>>7 -> walkers 2*half, 2*half+1,
// 6 rows each = 12 rows/thread. Per-output arithmetic identical to R1/R2.
__global__ __launch_bounds__(256) void k_route(
    const float* __restrict__ curr, const float* __restrict__ prev,
    float* __restrict__ outw, const float* __restrict__ w_in,
    const float* __restrict__ b_in, const float* __restrict__ w_out,
    const float* __restrict__ b_out, const float* __restrict__ rt_w1,
    const float* __restrict__ rt_b1, const float* __restrict__ rt_w2,
    const float* __restrict__ rt_b2, const float* __restrict__ pw1,
    const float* __restrict__ pb1, const float* __restrict__ pw2,
    const float* __restrict__ pb2, const int* __restrict__ start,
    float* __restrict__ pos) {
  __shared__ __align__(16) float sA[4][768];  // curr -> attn@V out
  __shared__ __align__(16) float sB[4][768];  // prev -> out-proj out
  __shared__ __align__(16) float sQ[4][768];  // q    -> relu(rt1)
  __shared__ __align__(16) float sK[4][768];  // k    -> final walks
  __shared__ __align__(16) float sV[4][768];  // v
  __shared__ __align__(16) float s_att[4][144];
  __shared__ __align__(16) float s_x[4][256];
  __shared__ __align__(16) float s_hid[4][64];

  int g0 = blockIdx.x * 4, t = threadIdx.x;
  int b = g0 >> 9;
  int c = t & 127, half = t >> 7, w0 = half * 2;
  {
    const float4* cg = (const float4*)(curr + (size_t)g0 * 768);
    const float4* pg = (const float4*)(prev + (size_t)g0 * 768);
    for (int i = t; i < 768; i += 256) {
      ((float4*)sA)[i] = cg[i];
      ((float4*)sB)[i] = pg[i];
    }
  }
  __syncthreads();

  // ---- QKV: 12 rows per thread ----
  float aq[12], ak[12], av[12];
#pragma unroll
  for (int l = 0; l < 12; ++l) {
    aq[l] = b_in[c];
    ak[l] = b_in[128 + c];
    av[l] = b_in[256 + c];
  }
  for (int j = 0; j < 128; j += 4) {
    float4 wq = *(const float4*)&w_in[(size_t)c * 128 + j];
    float4 wk = *(const float4*)&w_in[(size_t)(128 + c) * 128 + j];
    float4 wv = *(const float4*)&w_in[(size_t)(256 + c) * 128 + j];
#pragma unroll
    for (int l = 0; l < 12; ++l) {
      int wlk = w0 + (l / 6), row = l % 6;
      float4 c4 = *(const float4*)&sA[wlk][row * 128 + j];
      float4 p4 = *(const float4*)&sB[wlk][row * 128 + j];
      aq[l] += wq.x * c4.x + wq.y * c4.y + wq.z * c4.z + wq.w * c4.w;
      ak[l] += wk.x * p4.x + wk.y * p4.y + wk.z * p4.z + wk.w * p4.w;
      av[l] += wv.x * p4.x + wv.y * p4.y + wv.z * p4.z + wv.w * p4.w;
    }
  }
#pragma unroll
  for (int l = 0; l < 12; ++l) {
    int wlk = w0 + (l / 6), row = l % 6;
    sQ[wlk][row * 128 + c] = aq[l];
    sK[wlk][row * 128 + c] = ak[l];
    sV[wlk][row * 128 + c] = av[l];
  }
  __syncthreads();

  // ---- scores: 4 walkers x 4 heads x 6 x 6 = 576 entries ----
  for (int e = t; e < 576; e += 256) {
    int wlk = e / 144, r = e % 144;
    int h = r / 36, rr = r % 36, i = rr / 6, jj = rr % 6;
    float acc = 0.f;
#pragma unroll
    for (int d = 0; d < 32; d += 4) {
      float4 q4 = *(const float4*)&sQ[wlk][i * 128 + h * 32 + d];
      float4 k4 = *(const float4*)&sK[wlk][jj * 128 + h * 32 + d];
      acc += q4.x * k4.x + q4.y * k4.y + q4.z * k4.z + q4.w * k4.w;
    }
    s_att[wlk][r] = acc / sqrtf(32.0f);
  }
  __syncthreads();
  // ---- softmax: 4 walkers x 24 (h,i) rows ----
  if (t < 96) {
    int wlk = t / 24, r = t % 24;
    int h = r / 6, i = r % 6;
    float* row = &s_att[wlk][h * 36 + i * 6];
    float mx = row[0];
#pragma unroll
    for (int jj = 1; jj < 6; ++jj) mx = fmaxf(mx, row[jj]);
    float ex[6];
    float sum = 0.f;
#pragma unroll
    for (int jj = 0; jj < 6; ++jj) {
      ex[jj] = expf(row[jj] - mx);
      sum += ex[jj];
    }
#pragma unroll
    for (int jj = 0; jj < 6; ++jj) row[jj] = ex[jj] / sum;
  }
  __syncthreads();
  // ---- attn @ V ----
  {
    int h = c >> 5;
    float o[12];
#pragma unroll
    for (int l = 0; l < 12; ++l) {
      int wlk = w0 + (l / 6), row = l % 6;
      float acc = 0.f;
#pragma unroll
      for (int jj = 0; jj < 6; ++jj)
        acc += s_att[wlk][h * 36 + row * 6 + jj] * sV[wlk][jj * 128 + c];
      o[l] = acc;
    }
#pragma unroll
    for (int l = 0; l < 12; ++l) {
      int wlk = w0 + (l / 6), row = l % 6;
      sA[wlk][row * 128 + c] = o[l];
    }
  }
  __syncthreads();

  // ---- out-proj -> sB ----
  float ao[12];
#pragma unroll
  for (int l = 0; l < 12; ++l) ao[l] = b_out[c];
  for (int j = 0; j < 128; j += 4) {
    float4 w4 = *(const float4*)&w_out[(size_t)c * 128 + j];
#pragma unroll
    for (int l = 0; l < 12; ++l) {
      int wlk = w0 + (l / 6), row = l % 6;
      float4 o4 = *(const float4*)&sA[wlk][row * 128 + j];
      ao[l] += w4.x * o4.x + w4.y * o4.y + w4.z * o4.z + w4.w * o4.w;
    }
  }
  __syncthreads();
#pragma unroll
  for (int l = 0; l < 12; ++l) {
    int wlk = w0 + (l / 6), row = l % 6;
    sB[wlk][row * 128 + c] = ao[l];
  }
  __syncthreads();

  // ---- rt1 + relu -> sQ ----
  float a1[12];
#pragma unroll
  for (int l = 0; l < 12; ++l) a1[l] = rt_b1[c];
  for (int j = 0; j < 128; j += 4) {
    float4 w4 = *(const float4*)&rt_w1[(size_t)c * 128 + j];
#pragma unroll
    for (int l = 0; l < 12; ++l) {
      int wlk = w0 + (l / 6), row = l % 6;
      float4 o4 = *(const float4*)&sB[wlk][row * 128 + j];
      a1[l] += w4.x * o4.x + w4.y * o4.y + w4.z * o4.z + w4.w * o4.w;
    }
  }
#pragma unroll
  for (int l = 0; l < 12; ++l) {
    int wlk = w0 + (l / 6), row = l % 6;
    sQ[wlk][row * 128 + c] = fmaxf(a1[l], 0.f);
  }
  __syncthreads();

  // ---- rt2 -> sK + global out ----
  float a2[12];
#pragma unroll
  for (int l = 0; l < 12; ++l) a2[l] = rt_b2[c];
  for (int j = 0; j < 128; j += 4) {
    float4 w4 = *(const float4*)&rt_w2[(size_t)c * 128 + j];
#pragma unroll
    for (int l = 0; l < 12; ++l) {
      int wlk = w0 + (l / 6), row = l % 6;
      float4 o4 = *(const float4*)&sQ[wlk][row * 128 + j];
      a2[l] += w4.x * o4.x + w4.y * o4.y + w4.z * o4.z + w4.w * o4.w;
    }
  }
#pragma unroll
  for (int l = 0; l < 12; ++l) {
    int wlk = w0 + (l / 6), row = l % 6;
    outw[((size_t)(g0 + wlk)) * 768 + row * 128 + c] = a2[l];
    sK[wlk][row * 128 + c] = a2[l];
  }
  __syncthreads();

  // ---- predict ----
  for (int i = t; i < 512; i += 256) {
    int wlk = i >> 7, cc = i & 127;
    float sm = 0.f;
#pragma unroll
    for (int l = 1; l < 6; ++l) sm += sK[wlk][l * 128 + cc];
    s_x[wlk][cc] = sm / 5.0f - sK[wlk][cc];
    s_x[wlk][128 + cc] = sK[wlk][cc];
  }
  __syncthreads();
  {
    int wlk = t >> 6, h = t & 63;
    float acc = pb1[h];
#pragma unroll
    for (int j = 0; j < 256; j += 4) {
      float4 w4 = *(const float4*)&pw1[(size_t)h * 256 + j];
      float4 x4 = *(const float4*)&s_x[wlk][j];
      acc += w4.x * x4.x + w4.y * x4.y + w4.z * x4.z + w4.w * x4.w;
    }
    s_hid[wlk][h] = fmaxf(acc, 0.f);
  }
  __syncthreads();
  if (t < 12) {
    int wlk = t / 3, d = t % 3;
    float acc = pb2[d];
#pragma unroll
    for (int j = 0; j < 64; ++j) acc += pw2[d * 64 + j] * s_hid[wlk][j];
    float dd = tanhf(acc);
    int s = start[g0 + wlk];
    atomicAdd(&pos[((size_t)b * N_ + s) * 3 + d], dd);
  }
}

// ---------------- launcher ----------------
extern "C" void kernel_launch(void* const* d_in, const int* in_sizes, int n_in,
                              void* d_out, int out_size, void* d_ws,
                              size_t ws_size, hipStream_t stream) {
  const float* xyz = (const float*)d_in[0];
  const int* start = (const int*)d_in[1];
  const float* gumbel = (const float*)d_in[2];
  const float* enc_w1 = (const float*)d_in[3];
  const float* enc_b1 = (const float*)d_in[4];
  const float* enc_w2 = (const float*)d_in[5];
  const float* enc_b2 = (const float*)d_in[6];
  const float* beta_w = (const float*)d_in[7];
  const float* beta_b = (const float*)d_in[8];
  const float* gamma_w = (const float*)d_in[9];
  const float* gamma_b = (const float*)d_in[10];
  const float* attn_w_in = (const float*)d_in[11];
  const float* attn_b_in = (const float*)d_in[12];
  const float* attn_w_out = (const float*)d_in[13];
  const float* attn_b_out = (const float*)d_in[14];
  const float* rt_w1 = (const float*)d_in[15];
  const float* rt_b1 = (const float*)d_in[16];
  const float* rt_w2 = (const float*)d_in[17];
  const float* rt_b2 = (const float*)d_in[18];
  const float* pred_w1 = (const float*)d_in[19];
  const float* pred_b1 = (const float*)d_in[20];
  const float* pred_w2 = (const float*)d_in[21];
  const float* pred_b2 = (const float*)d_in[22];

  float* pos = (float*)d_out;
  float* ws = (float*)d_ws;
  float* feats = ws;                                   // 32MB
  float* wsel = feats + (size_t)B_ * N_ * C_;          // 6MB
  float* wA = wsel + (size_t)B_ * M_ * L_ * C_;        // 6MB
  float* wB = wA + (size_t)B_ * M_ * L_ * C_;          // 6MB
  int* idxbuf = (int*)(wB + (size_t)B_ * M_ * L_ * C_);

  hipMemcpyAsync(pos, xyz, (size_t)B_ * N_ * 3 * sizeof(float),
                 hipMemcpyDeviceToDevice, stream);
  k_encode<<<2048, 256, 0, stream>>>(xyz, enc_w1, enc_b1, enc_w2, enc_b2,
                                     feats);

  float* prevbuf = wsel;
  for (int t = 0; t < STEPS_; ++t) {
    k_step_init<<<2048, 128, 0, stream>>>(feats, start, idxbuf, wsel);
    for (int l = 0; l < L_ - 1; ++l) {
      const float* gptr =
          gumbel + (size_t)(t * (L_ - 1) + l) * B_ * M_ * K_;
      k_select<<<2048, 256, 0, stream>>>(pos, feats, idxbuf, wsel, beta_w,
                                         beta_b, gamma_w, gamma_b, gptr, l);
    }
    float* ob = (t & 1) ? wB : wA;
    k_route<<<512, 256, 0, stream>>>(
        wsel, prevbuf, ob, attn_w_in, attn_b_in, attn_w_out, attn_b_out, rt_w1,
        rt_b1, rt_w2, rt_b2, pred_w1, pred_b1, pred_w2, pred_b2, start, pos);
    prevbuf = ob;
  }
}